// Round 1
// baseline (227.841 us; speedup 1.0000x reference)
//
#include <hip/hip_runtime.h>
#include <math.h>

#define SEQ    1024
#define DK     16
#define NHEAD  16
#define NBATCH 8
#define LOG2E  1.4426950408889634f
#define NEGBIG -60000.0f

#define CH     128                       // keys per LDS chunk
#define NCH    (SEQ / CH)                // 8 chunks
#define KHI_STRIDE 40                    // LDS bytes per key row (32 data + 8 pad)
#define VT_STRIDE  272                   // LDS bytes per d row   (256 data + 16 pad)
#define KHI_CH (CH * KHI_STRIDE)         // 5120 B
#define VT_CH  (DK * VT_STRIDE)          // 4352 B
#define BUF_SZ (KHI_CH + VT_CH)          // 9472 B per buffer (x2 = 18.9 KB)

typedef __attribute__((ext_vector_type(4))) short  short4v;
typedef __attribute__((ext_vector_type(8))) short  short8v;
typedef __attribute__((ext_vector_type(2))) short  short2v;
typedef __attribute__((ext_vector_type(4))) float  float4v;
typedef __attribute__((ext_vector_type(2))) unsigned int uint2v;

static __device__ __forceinline__ float fast_exp2(float x) {
#if __has_builtin(__builtin_amdgcn_exp2f)
    return __builtin_amdgcn_exp2f(x);
#else
    return exp2f(x);
#endif
}

static __device__ __forceinline__ float4v mfma16(short4v a, short4v b, float4v c) {
#if __has_builtin(__builtin_amdgcn_mfma_f32_16x16x16bf16_1k)
    return __builtin_amdgcn_mfma_f32_16x16x16bf16_1k(a, b, c, 0, 0, 0);
#else
    float4v d = c;
    asm volatile("v_mfma_f32_16x16x16_bf16 %0, %1, %2, %0" : "+v"(d) : "v"(a), "v"(b));
    return d;
#endif
}

// K=32 MFMA: A/B = 8 bf16/lane (k = quad*8 + j). Fallback: two K=16 halves.
static __device__ __forceinline__ float4v mfma32(short8v a, short8v b, float4v c) {
#if __has_builtin(__builtin_amdgcn_mfma_f32_16x16x32_bf16)
    return __builtin_amdgcn_mfma_f32_16x16x32_bf16(a, b, c, 0, 0, 0);
#else
    short4v a0 = {a[0], a[1], a[2], a[3]}, a1 = {a[4], a[5], a[6], a[7]};
    short4v b0 = {b[0], b[1], b[2], b[3]}, b1 = {b[4], b[5], b[6], b[7]};
    c = mfma16(a0, b0, c);
    return mfma16(a1, b1, c);
#endif
}

static __device__ __forceinline__ unsigned bf16_rne(float x) {
    unsigned u = __float_as_uint(x);
    return (u + 0x7FFFu + ((u >> 16) & 1u)) >> 16;
}
static __device__ __forceinline__ float bf16_to_f(unsigned b) {
    return __uint_as_float(b << 16);
}
static __device__ __forceinline__ unsigned pk_bf16(float a, float b) {
#if __has_builtin(__builtin_amdgcn_cvt_pk_bf16_f32)
    short2v r = __builtin_amdgcn_cvt_pk_bf16_f32(a, b);
    return __builtin_bit_cast(unsigned, r);
#else
    return bf16_rne(a) | (bf16_rne(b) << 16);
#endif
}
static __device__ __forceinline__ short4v bc_s4(unsigned lo, unsigned hi) {
    uint2v u; u.x = lo; u.y = hi;
    return __builtin_bit_cast(short4v, u);
}

// ---------------- Fully fused flash pass -------------------------------------
// Single kernel, zero workspace. 1024 blocks, blockIdx&7 == b (XCD = batch),
// h fastest within batch so the 16 heads sharing a bias/mask q-slice run
// concurrently (L2/L3 dedupe -> ~1x compulsory HBM for the 67 MB bias+mask).
// K/V are converted fp32->bf16 (K row-major, V transposed) during LDS staging;
// bias+mask read raw per score fragment and folded into the MFMA C-init.
// MFMA core / Q hi-lo split / exp2 softmax / epilogue identical to the
// previously verified kernel.
__global__ __launch_bounds__(256, 4)
void sdpa_fused(const float* __restrict__ Q, const float* __restrict__ K,
                const float* __restrict__ V, const int* __restrict__ mask,
                const float* __restrict__ bias, float* __restrict__ out) {
    __shared__ __align__(16) char smem[2][BUF_SZ];

    const int tid  = threadIdx.x;
    const int wave = tid >> 6;
    const int lane = tid & 63;
    const int n    = lane & 15;
    const int g    = lane >> 4;
    const int permn = ((n >> 2) << 3) | (n & 3);   // tile-pair key permutation

    const int b  = blockIdx.x & 7;                 // XCD = batch
    const int j  = blockIdx.x >> 3;                // 0..127
    const int h  = j & 15;                         // heads fastest (bias L2 sharing)
    const int qt = j >> 4;                         // 0..7
    const int q0 = qt * 128;

    const size_t bh = (size_t)b * NHEAD + h;

    // 2 q-frags: q = q0 + f*64 + wave*16 + n. Q exact via hi/lo split.
    short4v qh[2], ql[2];
    const float* bRow[2];
    const int*   mRow[2];
    #pragma unroll
    for (int f = 0; f < 2; ++f) {
        const int qrow = q0 + f * 64 + wave * 16 + n;
        const float4 qv = *(const float4*)(Q + (bh * SEQ + qrow) * DK + g * 4);
        const float qsc = 0.25f * LOG2E;
        const float v[4] = {qv.x * qsc, qv.y * qsc, qv.z * qsc, qv.w * qsc};
        #pragma unroll
        for (int e = 0; e < 4; ++e) {
            const unsigned hu = bf16_rne(v[e]);
            qh[f][e] = (short)hu;
            ql[f][e] = (short)bf16_rne(v[e] - bf16_to_f(hu));
        }
        const size_t roff = ((size_t)b * SEQ + qrow) * (size_t)SEQ;
        bRow[f] = bias + roff;                     // per-lane q-row of bias[b]
        mRow[f] = mask + roff;
    }

    const float* Kb = K + bh * SEQ * DK;
    const float* Vb = V + bh * SEQ * DK;

    // Staging ownership:
    //  K: thread -> (key = tid>>1, half-row hh = tid&1): 2x float4 = 8 d's,
    //     pack 4x u32, one ds_write_b128 at key*40 + hh*16 (2-way banks, free).
    //  V: thread -> (key-pair k2 = tid>>2, d-quad dq = tid&3): 2x float4
    //     (even/odd key), pack key-pairs, 4x ds_write_b32 into transposed
    //     [d][key] rows (2-way banks, free).
    const int skey = tid >> 1, shh = tid & 1;
    const int sk2  = tid >> 2, sdq = tid & 3;

    float4v acc[2], accl[2];
    acc[0]  = (float4v){0.f, 0.f, 0.f, 0.f};
    acc[1]  = (float4v){0.f, 0.f, 0.f, 0.f};
    accl[0] = (float4v){0.f, 0.f, 0.f, 0.f};
    accl[1] = (float4v){0.f, 0.f, 0.f, 0.f};
    const short8v ones8 = {(short)0x3F80, (short)0x3F80, (short)0x3F80, (short)0x3F80,
                           (short)0x3F80, (short)0x3F80, (short)0x3F80, (short)0x3F80};

    float4 ka0, ka1, va0, va1;                     // in-flight staging regs

    auto stage_write = [&](char* s) {
        uint4 kp;
        kp.x = pk_bf16(ka0.x, ka0.y); kp.y = pk_bf16(ka0.z, ka0.w);
        kp.z = pk_bf16(ka1.x, ka1.y); kp.w = pk_bf16(ka1.z, ka1.w);
        *(uint4*)(s + skey * KHI_STRIDE + shh * 16) = kp;
        char* sv = s + KHI_CH;
        const float* pa = (const float*)&va0;
        const float* pb = (const float*)&va1;
        #pragma unroll
        for (int jj = 0; jj < 4; ++jj)
            *(unsigned*)(sv + (4 * sdq + jj) * VT_STRIDE + sk2 * 4) =
                pk_bf16(pa[jj], pb[jj]);
    };

    // prologue: stage chunk 0
    {
        ka0 = *(const float4*)(Kb + skey * DK + shh * 8);
        ka1 = *(const float4*)(Kb + skey * DK + shh * 8 + 4);
        va0 = *(const float4*)(Vb + (2 * sk2) * DK + sdq * 4);
        va1 = *(const float4*)(Vb + (2 * sk2 + 1) * DK + sdq * 4);
        stage_write(smem[0]);
    }
    __syncthreads();

    for (int c = 0; c < NCH; ++c) {
        const int cur = c & 1;
        if (c < NCH - 1) {                          // issue next-chunk loads early
            const int kc = (c + 1) * CH;
            ka0 = *(const float4*)(Kb + (kc + skey) * DK + shh * 8);
            ka1 = *(const float4*)(Kb + (kc + skey) * DK + shh * 8 + 4);
            va0 = *(const float4*)(Vb + (kc + 2 * sk2) * DK + sdq * 4);
            va1 = *(const float4*)(Vb + (kc + 2 * sk2 + 1) * DK + sdq * 4);
        }

        const char* khl = smem[cur];
        const char* vtl = smem[cur] + KHI_CH;

        #pragma unroll
        for (int tp = 0; tp < 4; ++tp) {
            const int rowA = tp * 32 + permn;
            const uint2 kAu = *(const uint2*)(khl + rowA * KHI_STRIDE + g * 8);
            const uint2 kBu = *(const uint2*)(khl + (rowA + 4) * KHI_STRIDE + g * 8);
            const uint4 vv  = *(const uint4*)(vtl + n * VT_STRIDE + tp * 64 + g * 16);
            const short4v khiA = bc_s4(kAu.x, kAu.y);
            const short4v khiB = bc_s4(kBu.x, kBu.y);
            const short8v vt8  = __builtin_bit_cast(short8v, vv);
            const int kk = c * CH + tp * 32 + 8 * g;  // this lane's key base

            #pragma unroll
            for (int f = 0; f < 2; ++f) {
                // raw bias/mask for 8 consecutive keys of q-row n
                const float4 bA = *(const float4*)(bRow[f] + kk);
                const float4 bB = *(const float4*)(bRow[f] + kk + 4);
                const int4   mA = *(const int4*)  (mRow[f] + kk);
                const int4   mB = *(const int4*)  (mRow[f] + kk + 4);

                // tile A scores: keys kk + r
                float4v sA;
                sA[0] = mA.x ? NEGBIG : bA.x * LOG2E;
                sA[1] = mA.y ? NEGBIG : bA.y * LOG2E;
                sA[2] = mA.z ? NEGBIG : bA.z * LOG2E;
                sA[3] = mA.w ? NEGBIG : bA.w * LOG2E;
                sA = mfma16(khiA, qh[f], sA);
                sA = mfma16(khiA, ql[f], sA);
                // tile B scores: keys kk + 4 + r
                float4v sB;
                sB[0] = mB.x ? NEGBIG : bB.x * LOG2E;
                sB[1] = mB.y ? NEGBIG : bB.y * LOG2E;
                sB[2] = mB.z ? NEGBIG : bB.z * LOG2E;
                sB[3] = mB.w ? NEGBIG : bB.w * LOG2E;
                sB = mfma16(khiB, qh[f], sB);
                sB = mfma16(khiB, ql[f], sB);

                const float pA0 = fast_exp2(sA[0]), pA1 = fast_exp2(sA[1]);
                const float pA2 = fast_exp2(sA[2]), pA3 = fast_exp2(sA[3]);
                const float pB0 = fast_exp2(sB[0]), pB1 = fast_exp2(sB[1]);
                const float pB2 = fast_exp2(sB[2]), pB3 = fast_exp2(sB[3]);

                // K=32 A-frag: [pA0..3, pB0..3] == keys 8g..8g+7 (k = quad*8+j)
                uint4 pu;
                pu.x = pk_bf16(pA0, pA1);
                pu.y = pk_bf16(pA2, pA3);
                pu.z = pk_bf16(pB0, pB1);
                pu.w = pk_bf16(pB2, pB3);
                const short8v pf8 = __builtin_bit_cast(short8v, pu);

                acc[f]  = mfma32(pf8, vt8,  acc[f]);    // O += P*V   (32 keys)
                accl[f] = mfma32(pf8, ones8, accl[f]);  // l += sum_k P
            }
        }

        if (c < NCH - 1) stage_write(smem[cur ^ 1]);   // write-late after compute
        __syncthreads();
    }

    // epilogue: accl[f][r] == l for q-row 4g+r — no cross-lane traffic
    #pragma unroll
    for (int f = 0; f < 2; ++f) {
        const size_t obase = bh * SEQ + q0 + f * 64 + wave * 16;
        #pragma unroll
        for (int r = 0; r < 4; ++r) {
            out[(obase + 4 * g + r) * DK + n] = acc[f][r] / accl[f][r];
        }
    }
}

extern "C" void kernel_launch(void* const* d_in, const int* in_sizes, int n_in,
                              void* d_out, int out_size, void* d_ws, size_t ws_size,
                              hipStream_t stream) {
    (void)in_sizes; (void)n_in; (void)out_size; (void)d_ws; (void)ws_size;
    const float* Q    = (const float*)d_in[0];
    const float* K    = (const float*)d_in[1];
    const float* V    = (const float*)d_in[2];
    const int*   mask = (const int*)  d_in[3];
    const float* bias = (const float*)d_in[4];
    float* out = (float*)d_out;

    sdpa_fused<<<NBATCH * NHEAD * (SEQ / 128), 256, 0, stream>>>(Q, K, V, mask, bias, out);
}

// Round 2
// 224.892 us; speedup vs baseline: 1.0131x; 1.0131x over previous
//
#include <hip/hip_runtime.h>
#include <math.h>

#define SEQ    1024
#define DK     16
#define NHEAD  16
#define NBATCH 8
#define LOG2E  1.4426950408889634f
#define NEGBIG -60000.0f

#define CH     128                       // keys per LDS chunk
#define NCH    (SEQ / CH)                // 8 chunks
#define KHI_STRIDE 40                    // LDS bytes per key row (32 data + 8 pad)
#define VT_STRIDE  272                   // LDS bytes per d row   (256 data + 16 pad)
#define KHI_CH (CH * KHI_STRIDE)         // 5120 B
#define VT_CH  (DK * VT_STRIDE)          // 4352 B
#define BUF_SZ (KHI_CH + VT_CH)          // 9472 B per buffer (x2 = 18.9 KB)

typedef __attribute__((ext_vector_type(4))) short  short4v;
typedef __attribute__((ext_vector_type(8))) short  short8v;
typedef __attribute__((ext_vector_type(2))) short  short2v;
typedef __attribute__((ext_vector_type(4))) float  float4v;
typedef __attribute__((ext_vector_type(2))) unsigned int uint2v;

static __device__ __forceinline__ float fast_exp2(float x) {
#if __has_builtin(__builtin_amdgcn_exp2f)
    return __builtin_amdgcn_exp2f(x);
#else
    return exp2f(x);
#endif
}

static __device__ __forceinline__ float4v mfma16(short4v a, short4v b, float4v c) {
#if __has_builtin(__builtin_amdgcn_mfma_f32_16x16x16bf16_1k)
    return __builtin_amdgcn_mfma_f32_16x16x16bf16_1k(a, b, c, 0, 0, 0);
#else
    float4v d = c;
    asm volatile("v_mfma_f32_16x16x16_bf16 %0, %1, %2, %0" : "+v"(d) : "v"(a), "v"(b));
    return d;
#endif
}

// K=32 MFMA: A/B = 8 bf16/lane (k = quad*8 + j). Fallback: two K=16 halves.
static __device__ __forceinline__ float4v mfma32(short8v a, short8v b, float4v c) {
#if __has_builtin(__builtin_amdgcn_mfma_f32_16x16x32_bf16)
    return __builtin_amdgcn_mfma_f32_16x16x32_bf16(a, b, c, 0, 0, 0);
#else
    short4v a0 = {a[0], a[1], a[2], a[3]}, a1 = {a[4], a[5], a[6], a[7]};
    short4v b0 = {b[0], b[1], b[2], b[3]}, b1 = {b[4], b[5], b[6], b[7]};
    c = mfma16(a0, b0, c);
    return mfma16(a1, b1, c);
#endif
}

static __device__ __forceinline__ unsigned bf16_rne(float x) {
    unsigned u = __float_as_uint(x);
    return (u + 0x7FFFu + ((u >> 16) & 1u)) >> 16;
}
static __device__ __forceinline__ float bf16_to_f(unsigned b) {
    return __uint_as_float(b << 16);
}
static __device__ __forceinline__ unsigned pk_bf16(float a, float b) {
#if __has_builtin(__builtin_amdgcn_cvt_pk_bf16_f32)
    short2v r = __builtin_amdgcn_cvt_pk_bf16_f32(a, b);
    return __builtin_bit_cast(unsigned, r);
#else
    return bf16_rne(a) | (bf16_rne(b) << 16);
#endif
}
static __device__ __forceinline__ short4v bc_s4(unsigned lo, unsigned hi) {
    uint2v u; u.x = lo; u.y = hi;
    return __builtin_bit_cast(short4v, u);
}

// ---------------- Fully fused flash pass -------------------------------------
// Single kernel, zero workspace. 1024 blocks, blockIdx&7 == b (XCD = batch),
// h fastest within batch so the 16 heads sharing a bias/mask q-slice run
// concurrently (L2 dedupe -> ~1x compulsory HBM for the 67 MB bias+mask).
// K/V converted fp32->bf16 (K row-major, V transposed) during LDS staging.
// Bias+mask: per-tp software pipeline — raw loads for tp+1 issued before tp's
// compute, held in double-buffered regs, so the s_waitcnt sits one full tp of
// MFMA/exp2 work after issue (the round-1 version had zero distance and
// latency-collapsed to 24% VALUBusy).
__global__ __launch_bounds__(256, 3)
void sdpa_fused(const float* __restrict__ Q, const float* __restrict__ K,
                const float* __restrict__ V, const int* __restrict__ mask,
                const float* __restrict__ bias, float* __restrict__ out) {
    __shared__ __align__(16) char smem[2][BUF_SZ];

    const int tid  = threadIdx.x;
    const int wave = tid >> 6;
    const int lane = tid & 63;
    const int n    = lane & 15;
    const int g    = lane >> 4;
    const int permn = ((n >> 2) << 3) | (n & 3);   // tile-pair key permutation

    const int b  = blockIdx.x & 7;                 // XCD = batch
    const int j  = blockIdx.x >> 3;                // 0..127
    const int h  = j & 15;                         // heads fastest (bias L2 sharing)
    const int qt = j >> 4;                         // 0..7
    const int q0 = qt * 128;

    const size_t bh = (size_t)b * NHEAD + h;

    // Uniform (SGPR) bases for bias/mask of this batch; per-lane 32-bit row offs.
    const float* bBase = bias + (size_t)b * SEQ * SEQ;
    const int*   mBase = mask + (size_t)b * SEQ * SEQ;

    // 2 q-frags: q = q0 + f*64 + wave*16 + n. Q exact via hi/lo split.
    short4v qh[2], ql[2];
    int rowoff[2];
    #pragma unroll
    for (int f = 0; f < 2; ++f) {
        const int qrow = q0 + f * 64 + wave * 16 + n;
        const float4 qv = *(const float4*)(Q + (bh * SEQ + qrow) * DK + g * 4);
        const float qsc = 0.25f * LOG2E;
        const float v[4] = {qv.x * qsc, qv.y * qsc, qv.z * qsc, qv.w * qsc};
        #pragma unroll
        for (int e = 0; e < 4; ++e) {
            const unsigned hu = bf16_rne(v[e]);
            qh[f][e] = (short)hu;
            ql[f][e] = (short)bf16_rne(v[e] - bf16_to_f(hu));
        }
        rowoff[f] = qrow * SEQ;                    // element offset into [S,S] slab
    }

    const float* Kb = K + bh * SEQ * DK;
    const float* Vb = V + bh * SEQ * DK;

    // Staging ownership:
    //  K: thread -> (key = tid>>1, half-row hh = tid&1): 2x float4 = 8 d's,
    //     one ds_write_b128 at key*40 + hh*16 (2-way banks, free).
    //  V: thread -> (key-pair k2 = tid>>2, d-quad dq = tid&3): 2x float4
    //     (even/odd key), 4x ds_write_b32 into transposed rows (2-way, free).
    const int skey = tid >> 1, shh = tid & 1;
    const int sk2  = tid >> 2, sdq = tid & 3;

    float4v acc[2], accl[2];
    acc[0]  = (float4v){0.f, 0.f, 0.f, 0.f};
    acc[1]  = (float4v){0.f, 0.f, 0.f, 0.f};
    accl[0] = (float4v){0.f, 0.f, 0.f, 0.f};
    accl[1] = (float4v){0.f, 0.f, 0.f, 0.f};
    const short8v ones8 = {(short)0x3F80, (short)0x3F80, (short)0x3F80, (short)0x3F80,
                           (short)0x3F80, (short)0x3F80, (short)0x3F80, (short)0x3F80};

    float4 ka0, ka1, va0, va1;                     // in-flight K/V staging regs

    auto stage_write = [&](char* s) {
        uint4 kp;
        kp.x = pk_bf16(ka0.x, ka0.y); kp.y = pk_bf16(ka0.z, ka0.w);
        kp.z = pk_bf16(ka1.x, ka1.y); kp.w = pk_bf16(ka1.z, ka1.w);
        *(uint4*)(s + skey * KHI_STRIDE + shh * 16) = kp;
        char* sv = s + KHI_CH;
        const float* pa = (const float*)&va0;
        const float* pb = (const float*)&va1;
        #pragma unroll
        for (int jj = 0; jj < 4; ++jj)
            *(unsigned*)(sv + (4 * sdq + jj) * VT_STRIDE + sk2 * 4) =
                pk_bf16(pa[jj], pb[jj]);
    };

    // Bias/mask raw pipeline: double-buffered regs, 1-tp prefetch distance.
    float4 rb[2][2][2];                            // [buf][f][tile]
    int4   rm[2][2][2];

    // prologue: stage K/V chunk 0; issue bias/mask for (c=0, tp=0) into buf 0
    {
        ka0 = *(const float4*)(Kb + skey * DK + shh * 8);
        ka1 = *(const float4*)(Kb + skey * DK + shh * 8 + 4);
        va0 = *(const float4*)(Vb + (2 * sk2) * DK + sdq * 4);
        va1 = *(const float4*)(Vb + (2 * sk2 + 1) * DK + sdq * 4);
        const int kk0 = 8 * g;
        #pragma unroll
        for (int f = 0; f < 2; ++f) {
            rb[0][f][0] = *(const float4*)(bBase + rowoff[f] + kk0);
            rb[0][f][1] = *(const float4*)(bBase + rowoff[f] + kk0 + 4);
            rm[0][f][0] = *(const int4*)  (mBase + rowoff[f] + kk0);
            rm[0][f][1] = *(const int4*)  (mBase + rowoff[f] + kk0 + 4);
        }
        stage_write(smem[0]);
    }
    __syncthreads();

    for (int c = 0; c < NCH; ++c) {
        const int cur = c & 1;
        if (c < NCH - 1) {                          // issue next-chunk K/V early
            const int kc = (c + 1) * CH;
            ka0 = *(const float4*)(Kb + (kc + skey) * DK + shh * 8);
            ka1 = *(const float4*)(Kb + (kc + skey) * DK + shh * 8 + 4);
            va0 = *(const float4*)(Vb + (kc + 2 * sk2) * DK + sdq * 4);
            va1 = *(const float4*)(Vb + (kc + 2 * sk2 + 1) * DK + sdq * 4);
        }

        const char* khl = smem[cur];
        const char* vtl = smem[cur] + KHI_CH;

        #pragma unroll
        for (int tp = 0; tp < 4; ++tp) {
            const int buf = tp & 1;
            // 1) issue raw bias/mask for the NEXT tp (possibly next chunk)
            if (!(c == NCH - 1 && tp == 3)) {
                const int nc  = (tp == 3) ? c + 1 : c;
                const int ntp = (tp + 1) & 3;
                const int nkk = nc * CH + ntp * 32 + 8 * g;
                #pragma unroll
                for (int f = 0; f < 2; ++f) {
                    rb[buf ^ 1][f][0] = *(const float4*)(bBase + rowoff[f] + nkk);
                    rb[buf ^ 1][f][1] = *(const float4*)(bBase + rowoff[f] + nkk + 4);
                    rm[buf ^ 1][f][0] = *(const int4*)  (mBase + rowoff[f] + nkk);
                    rm[buf ^ 1][f][1] = *(const int4*)  (mBase + rowoff[f] + nkk + 4);
                }
            }

            // 2) LDS fragments for this tp
            const int rowA = tp * 32 + permn;
            const uint2 kAu = *(const uint2*)(khl + rowA * KHI_STRIDE + g * 8);
            const uint2 kBu = *(const uint2*)(khl + (rowA + 4) * KHI_STRIDE + g * 8);
            const uint4 vv  = *(const uint4*)(vtl + n * VT_STRIDE + tp * 64 + g * 16);
            const short4v khiA = bc_s4(kAu.x, kAu.y);
            const short4v khiB = bc_s4(kBu.x, kBu.y);
            const short8v vt8  = __builtin_bit_cast(short8v, vv);

            // 3) compute using the buffer issued one tp ago
            #pragma unroll
            for (int f = 0; f < 2; ++f) {
                const float4 bA = rb[buf][f][0];
                const float4 bB = rb[buf][f][1];
                const int4   mA = rm[buf][f][0];
                const int4   mB = rm[buf][f][1];

                float4v sA;
                sA[0] = mA.x ? NEGBIG : bA.x * LOG2E;
                sA[1] = mA.y ? NEGBIG : bA.y * LOG2E;
                sA[2] = mA.z ? NEGBIG : bA.z * LOG2E;
                sA[3] = mA.w ? NEGBIG : bA.w * LOG2E;
                sA = mfma16(khiA, qh[f], sA);
                sA = mfma16(khiA, ql[f], sA);
                float4v sB;
                sB[0] = mB.x ? NEGBIG : bB.x * LOG2E;
                sB[1] = mB.y ? NEGBIG : bB.y * LOG2E;
                sB[2] = mB.z ? NEGBIG : bB.z * LOG2E;
                sB[3] = mB.w ? NEGBIG : bB.w * LOG2E;
                sB = mfma16(khiB, qh[f], sB);
                sB = mfma16(khiB, ql[f], sB);

                const float pA0 = fast_exp2(sA[0]), pA1 = fast_exp2(sA[1]);
                const float pA2 = fast_exp2(sA[2]), pA3 = fast_exp2(sA[3]);
                const float pB0 = fast_exp2(sB[0]), pB1 = fast_exp2(sB[1]);
                const float pB2 = fast_exp2(sB[2]), pB3 = fast_exp2(sB[3]);

                // K=32 A-frag: [pA0..3, pB0..3] == keys 8g..8g+7 (k = quad*8+j)
                uint4 pu;
                pu.x = pk_bf16(pA0, pA1);
                pu.y = pk_bf16(pA2, pA3);
                pu.z = pk_bf16(pB0, pB1);
                pu.w = pk_bf16(pB2, pB3);
                const short8v pf8 = __builtin_bit_cast(short8v, pu);

                acc[f]  = mfma32(pf8, vt8,  acc[f]);    // O += P*V   (32 keys)
                accl[f] = mfma32(pf8, ones8, accl[f]);  // l += sum_k P
            }
        }

        if (c < NCH - 1) stage_write(smem[cur ^ 1]);   // write-late after compute
        __syncthreads();
    }

    // epilogue: accl[f][r] == l for q-row 4g+r — no cross-lane traffic
    #pragma unroll
    for (int f = 0; f < 2; ++f) {
        const size_t obase = bh * SEQ + q0 + f * 64 + wave * 16;
        #pragma unroll
        for (int r = 0; r < 4; ++r) {
            out[(obase + 4 * g + r) * DK + n] = acc[f][r] / accl[f][r];
        }
    }
}

extern "C" void kernel_launch(void* const* d_in, const int* in_sizes, int n_in,
                              void* d_out, int out_size, void* d_ws, size_t ws_size,
                              hipStream_t stream) {
    (void)in_sizes; (void)n_in; (void)out_size; (void)d_ws; (void)ws_size;
    const float* Q    = (const float*)d_in[0];
    const float* K    = (const float*)d_in[1];
    const float* V    = (const float*)d_in[2];
    const int*   mask = (const int*)  d_in[3];
    const float* bias = (const float*)d_in[4];
    float* out = (float*)d_out;

    sdpa_fused<<<NBATCH * NHEAD * (SEQ / 128), 256, 0, stream>>>(Q, K, V, mask, bias, out);
}

// Round 4
// 194.320 us; speedup vs baseline: 1.1725x; 1.1573x over previous
//
#include <hip/hip_runtime.h>
#include <hip/hip_fp16.h>
#include <math.h>

#define SEQ    1024
#define DK     16
#define NHEAD  16
#define NBATCH 8
#define LOG2E  1.4426950408889634f
#define NEGBIG -60000.0f

#define CH     64                        // keys per LDS chunk
#define NCH    (SEQ / CH)                // 16 chunks
#define KHI_STRIDE 40                    // LDS bytes per key row (32 data + 8 pad)
#define VT_STRIDE  144                   // LDS bytes per d row   (128 data + 16 pad)
#define KHI_CH (CH * KHI_STRIDE)         // 2560 B
#define VT_CH  (DK * VT_STRIDE)          // 2304 B
#define BIAS_CH (128 * CH * 2)           // 16384 B (128 q-rows x 64 keys, fp16)
#define BUF_SZ (KHI_CH + VT_CH + BIAS_CH)// 21248 B per buffer (x2 = 42.5 KB)

typedef __attribute__((ext_vector_type(4))) short  short4v;
typedef __attribute__((ext_vector_type(8))) short  short8v;
typedef __attribute__((ext_vector_type(2))) short  short2v;
typedef __attribute__((ext_vector_type(4))) float  float4v;
typedef __attribute__((ext_vector_type(2))) unsigned int uint2v;

static __device__ __forceinline__ float fast_exp2(float x) {
#if __has_builtin(__builtin_amdgcn_exp2f)
    return __builtin_amdgcn_exp2f(x);
#else
    return exp2f(x);
#endif
}

static __device__ __forceinline__ float4v mfma16(short4v a, short4v b, float4v c) {
#if __has_builtin(__builtin_amdgcn_mfma_f32_16x16x16bf16_1k)
    return __builtin_amdgcn_mfma_f32_16x16x16bf16_1k(a, b, c, 0, 0, 0);
#else
    float4v d = c;
    asm volatile("v_mfma_f32_16x16x16_bf16 %0, %1, %2, %0" : "+v"(d) : "v"(a), "v"(b));
    return d;
#endif
}

// K=32 MFMA: A/B = 8 bf16/lane (k = quad*8 + j). Fallback: two K=16 halves.
static __device__ __forceinline__ float4v mfma32(short8v a, short8v b, float4v c) {
#if __has_builtin(__builtin_amdgcn_mfma_f32_16x16x32_bf16)
    return __builtin_amdgcn_mfma_f32_16x16x32_bf16(a, b, c, 0, 0, 0);
#else
    short4v a0 = {a[0], a[1], a[2], a[3]}, a1 = {a[4], a[5], a[6], a[7]};
    short4v b0 = {b[0], b[1], b[2], b[3]}, b1 = {b[4], b[5], b[6], b[7]};
    c = mfma16(a0, b0, c);
    return mfma16(a1, b1, c);
#endif
}

static __device__ __forceinline__ unsigned bf16_rne(float x) {
    unsigned u = __float_as_uint(x);
    return (u + 0x7FFFu + ((u >> 16) & 1u)) >> 16;
}
static __device__ __forceinline__ float bf16_to_f(unsigned b) {
    return __uint_as_float(b << 16);
}
static __device__ __forceinline__ unsigned pk_bf16(float a, float b) {
#if __has_builtin(__builtin_amdgcn_cvt_pk_bf16_f32)
    short2v r = __builtin_amdgcn_cvt_pk_bf16_f32(a, b);
    return __builtin_bit_cast(unsigned, r);
#else
    return bf16_rne(a) | (bf16_rne(b) << 16);
#endif
}
static __device__ __forceinline__ short4v bc_s4(unsigned lo, unsigned hi) {
    uint2v u; u.x = lo; u.y = hi;
    return __builtin_bit_cast(short4v, u);
}

// ---------------- Fully fused flash pass -------------------------------------
// Single kernel, zero workspace. 1024 blocks, blockIdx&7 == b (XCD = batch),
// h fastest within batch (16 heads share each bias/mask slice via L2).
// Per CH=64 chunk, every block stages:
//   K   -> bf16 row-major LDS   (threads 0..127)
//   V   -> bf16 transposed LDS  (threads 128..255)
//   bias+mask -> fp16 fragment-major LDS (all threads; mask-select + *LOG2E
//               applied at staging, like the old prep kernel's biasp)
// Loads for chunk c+1 issue at the TOP of chunk c's compute; conversion +
// ds_write happen AFTER compute (deferred-consumer shape the compiler keeps
// hoisted — round 2 showed plain reg-to-reg "prefetch" gets sunk to its use).
// sched_barrier(0) pins the issue block. Compute reads bias via contiguous
// 1KB-per-wave b128 (conflict-free; XOR swizzle caps staging write at 4-way).
// (Round 3 submission of this exact kernel died to a container-level infra
// failure with no verdict; audit found no OOB/hang path — resubmitting.)
__global__ __launch_bounds__(256, 3)
void sdpa_fused(const float* __restrict__ Q, const float* __restrict__ K,
                const float* __restrict__ V, const int* __restrict__ mask,
                const float* __restrict__ bias, float* __restrict__ out) {
    __shared__ __align__(16) char smem[2][BUF_SZ];

    const int tid  = threadIdx.x;
    const int wave = tid >> 6;
    const int lane = tid & 63;
    const int n    = lane & 15;
    const int g    = lane >> 4;
    const int permn = ((n >> 2) << 3) | (n & 3);   // tile-pair key permutation
    const int lso  = (lane ^ (g << 2)) * 16;       // swizzled bias slot byte off

    const int b  = blockIdx.x & 7;                 // XCD = batch
    const int j  = blockIdx.x >> 3;                // 0..127
    const int h  = j & 15;                         // heads fastest (bias L2 share)
    const int qt = j >> 4;                         // 0..7
    const int q0 = qt * 128;
    const size_t bh = (size_t)b * NHEAD + h;

    // ---- Q fragments (hi/lo split; exact QK via 2 MFMAs) ----
    short4v qh[2], ql[2];
    #pragma unroll
    for (int f = 0; f < 2; ++f) {
        const int qrow = q0 + f * 64 + wave * 16 + n;
        const float4 qv = *(const float4*)(Q + (bh * SEQ + qrow) * DK + g * 4);
        const float qsc = 0.25f * LOG2E;
        const float v[4] = {qv.x * qsc, qv.y * qsc, qv.z * qsc, qv.w * qsc};
        #pragma unroll
        for (int e = 0; e < 4; ++e) {
            const unsigned hu = bf16_rne(v[e]);
            qh[f][e] = (short)hu;
            ql[f][e] = (short)bf16_rne(v[e] - bf16_to_f(hu));
        }
    }

    const float* Kb = K + bh * SEQ * DK;
    const float* Vb = V + bh * SEQ * DK;

    // K/V staging roles (wave-uniform split):
    const int skey = tid >> 1, shh = tid & 1;                 // tid < 128 : K
    const int sk2  = (tid - 128) >> 2, sdq = (tid - 128) & 3; // tid >= 128 : V

    // bias stager coords: thread -> (row group brow, key-quad kq4)
    const int brow = tid >> 4;                 // 0..15
    const int kq4  = tid & 15;                 // float4 index in 64-key chunk
    const int tpo  = kq4 >> 3;                 // tile-pair
    const int g_s  = (kq4 >> 1) & 3;           // key-octet
    const int half_s = kq4 & 1;                // low/high 4 keys of octet
    const int up   = 16 * g_s + (brow ^ (g_s << 2));   // swizzled 16B slot
    const int boff = up * 16 + half_s * 8;
    const float* bRow0 = bias + (size_t)b * SEQ * SEQ + (size_t)(q0 + brow) * SEQ + kq4 * 4;
    const int*   mRow0 = mask + (size_t)b * SEQ * SEQ + (size_t)(q0 + brow) * SEQ + kq4 * 4;

    float4v acc[2], accl[2];
    acc[0]  = (float4v){0.f, 0.f, 0.f, 0.f};
    acc[1]  = (float4v){0.f, 0.f, 0.f, 0.f};
    accl[0] = (float4v){0.f, 0.f, 0.f, 0.f};
    accl[1] = (float4v){0.f, 0.f, 0.f, 0.f};
    const short8v ones8 = {(short)0x3F80, (short)0x3F80, (short)0x3F80, (short)0x3F80,
                           (short)0x3F80, (short)0x3F80, (short)0x3F80, (short)0x3F80};

    float4 pb[8]; int4 pm[8];                  // in-flight bias/mask (8 passes)
    float4 kv0, kv1;                           // in-flight K or V

    auto issue = [&](int kc) {
        #pragma unroll
        for (int p = 0; p < 8; ++p) {
            pb[p] = *(const float4*)(bRow0 + (size_t)p * 16 * SEQ + kc);
            pm[p] = *(const int4*)  (mRow0 + (size_t)p * 16 * SEQ + kc);
        }
        if (tid < 128) {
            kv0 = *(const float4*)(Kb + (kc + skey) * DK + shh * 8);
            kv1 = *(const float4*)(Kb + (kc + skey) * DK + shh * 8 + 4);
        } else {
            kv0 = *(const float4*)(Vb + (kc + 2 * sk2) * DK + sdq * 4);
            kv1 = *(const float4*)(Vb + (kc + 2 * sk2 + 1) * DK + sdq * 4);
        }
    };

    auto commit = [&](char* s) {
        if (tid < 128) {
            uint4 kp;
            kp.x = pk_bf16(kv0.x, kv0.y); kp.y = pk_bf16(kv0.z, kv0.w);
            kp.z = pk_bf16(kv1.x, kv1.y); kp.w = pk_bf16(kv1.z, kv1.w);
            *(uint4*)(s + skey * KHI_STRIDE + shh * 16) = kp;
        } else {
            char* sv = s + KHI_CH;
            const float* pa = (const float*)&kv0;
            const float* pv = (const float*)&kv1;
            #pragma unroll
            for (int jj = 0; jj < 4; ++jj)
                *(unsigned*)(sv + (4 * sdq + jj) * VT_STRIDE + sk2 * 4) =
                    pk_bf16(pa[jj], pv[jj]);
        }
        char* bs = s + KHI_CH + VT_CH;
        #pragma unroll
        for (int p = 0; p < 8; ++p) {
            const float4 bv = pb[p]; const int4 mv = pm[p];
            const __half2 lo = __floats2half2_rn(mv.x ? NEGBIG : bv.x * LOG2E,
                                                 mv.y ? NEGBIG : bv.y * LOG2E);
            const __half2 hi = __floats2half2_rn(mv.z ? NEGBIG : bv.z * LOG2E,
                                                 mv.w ? NEGBIG : bv.w * LOG2E);
            uint2 u;
            u.x = __builtin_bit_cast(unsigned, lo);
            u.y = __builtin_bit_cast(unsigned, hi);
            // block index (f*2+tp)*4 + w  ->  f = p>>2, w = p&3
            *(uint2*)(bs + ((p >> 2) * 2 + tpo) * 4096 + (p & 3) * 1024 + boff) = u;
        }
    };

    // prologue: stage chunk 0
    issue(0);
    commit(smem[0]);
    __syncthreads();

    for (int c = 0; c < NCH; ++c) {
        const int cur = c & 1;
        if (c < NCH - 1) issue((c + 1) * CH);   // chunk-distance prefetch
#if __has_builtin(__builtin_amdgcn_sched_barrier)
        __builtin_amdgcn_sched_barrier(0);      // pin loads above compute
#endif
        const char* khl = smem[cur];
        const char* vtl = smem[cur] + KHI_CH;
        const char* bsl = smem[cur] + KHI_CH + VT_CH;

        #pragma unroll
        for (int tp = 0; tp < 2; ++tp) {
            const int rowA = tp * 32 + permn;
            const uint2 kAu = *(const uint2*)(khl + rowA * KHI_STRIDE + g * 8);
            const uint2 kBu = *(const uint2*)(khl + (rowA + 4) * KHI_STRIDE + g * 8);
            const uint4 vv  = *(const uint4*)(vtl + n * VT_STRIDE + tp * 64 + g * 16);
            const short4v khiA = bc_s4(kAu.x, kAu.y);
            const short4v khiB = bc_s4(kBu.x, kBu.y);
            const short8v vt8  = __builtin_bit_cast(short8v, vv);

            #pragma unroll
            for (int f = 0; f < 2; ++f) {
                const uint4 bb = *(const uint4*)(bsl + ((f * 2 + tp) * 4 + wave) * 1024 + lso);
                const float2 a01 = __half22float2(__builtin_bit_cast(__half2, bb.x));
                const float2 a23 = __half22float2(__builtin_bit_cast(__half2, bb.y));
                float4v sA; sA[0] = a01.x; sA[1] = a01.y; sA[2] = a23.x; sA[3] = a23.y;
                sA = mfma16(khiA, qh[f], sA);
                sA = mfma16(khiA, ql[f], sA);
                const float2 b01 = __half22float2(__builtin_bit_cast(__half2, bb.z));
                const float2 b23 = __half22float2(__builtin_bit_cast(__half2, bb.w));
                float4v sB; sB[0] = b01.x; sB[1] = b01.y; sB[2] = b23.x; sB[3] = b23.y;
                sB = mfma16(khiB, qh[f], sB);
                sB = mfma16(khiB, ql[f], sB);

                const float pA0 = fast_exp2(sA[0]), pA1 = fast_exp2(sA[1]);
                const float pA2 = fast_exp2(sA[2]), pA3 = fast_exp2(sA[3]);
                const float pB0 = fast_exp2(sB[0]), pB1 = fast_exp2(sB[1]);
                const float pB2 = fast_exp2(sB[2]), pB3 = fast_exp2(sB[3]);

                // K=32 A-frag: [pA0..3, pB0..3] == keys 8g..8g+7 (k = quad*8+j)
                uint4 pu;
                pu.x = pk_bf16(pA0, pA1);
                pu.y = pk_bf16(pA2, pA3);
                pu.z = pk_bf16(pB0, pB1);
                pu.w = pk_bf16(pB2, pB3);
                const short8v pf8 = __builtin_bit_cast(short8v, pu);

                acc[f]  = mfma32(pf8, vt8,  acc[f]);    // O += P*V   (32 keys)
                accl[f] = mfma32(pf8, ones8, accl[f]);  // l += sum_k P
            }
        }

        if (c < NCH - 1) commit(smem[cur ^ 1]);  // convert+write after compute
        __syncthreads();
    }

    // epilogue: accl[f][r] == l for q-row 4g+r — no cross-lane traffic
    #pragma unroll
    for (int f = 0; f < 2; ++f) {
        const size_t obase = bh * SEQ + q0 + f * 64 + wave * 16;
        #pragma unroll
        for (int r = 0; r < 4; ++r) {
            out[(obase + 4 * g + r) * DK + n] = acc[f][r] / accl[f][r];
        }
    }
}

extern "C" void kernel_launch(void* const* d_in, const int* in_sizes, int n_in,
                              void* d_out, int out_size, void* d_ws, size_t ws_size,
                              hipStream_t stream) {
    (void)in_sizes; (void)n_in; (void)out_size; (void)d_ws; (void)ws_size;
    const float* Q    = (const float*)d_in[0];
    const float* K    = (const float*)d_in[1];
    const float* V    = (const float*)d_in[2];
    const int*   mask = (const int*)  d_in[3];
    const float* bias = (const float*)d_in[4];
    float* out = (float*)d_out;

    sdpa_fused<<<NBATCH * NHEAD * (SEQ / 128), 256, 0, stream>>>(Q, K, V, mask, bias, out);
}